// Round 1
// baseline (149.005 us; speedup 1.0000x reference)
//
#include <hip/hip_runtime.h>
#include <hip/hip_bf16.h>

typedef _Float16 f16;
typedef _Float16 half8 __attribute__((ext_vector_type(8)));
typedef float floatx4 __attribute__((ext_vector_type(4)));

#define BM 64

// ---- ws layout (f16 element offsets) ----
#define WA_OFF 0         // 65536 f16  : Wa  [256K x 256N] frag order (NT=16,KT=8)
#define WB_OFF 65536     // 18432 f16  : Wb  [128K x 144N] (NT=9, KT=4)  cols: 0-127=W2, 128-143=W12
#define WC_OFF 83968     // 2048 f16   : Wc  [128K x 16N]  (NT=1, KT=4)  cols 0-3 = W22
#define WF2_OFF 86016    // 4096 f16   : Wf2 [4][32K x 32N] (per e: NT=2, KT=1)
#define WSF_BYTE_OFF 180224
// wsf (float offsets)
#define BA_OFF 0      // 256: b1 | bf1
#define BB_OFF 256    // 144: b2 | b12
#define BCC_OFF 400   // 4  : b22
#define BF2_OFF 404   // 128: bf2
#define WFIN_OFF 532  // 32
#define BFIN_OFF 564  // 1

__global__ __launch_bounds__(256) void prep_kernel(
    const float* __restrict__ ctx, const float* __restrict__ W1,
    const float* __restrict__ b1, const float* __restrict__ W2,
    const float* __restrict__ b2, const float* __restrict__ W12,
    const float* __restrict__ b12, const float* __restrict__ W22,
    const float* __restrict__ b22, const float* __restrict__ Wf1,
    const float* __restrict__ bf1, const float* __restrict__ Wf2,
    const float* __restrict__ bf2, const float* __restrict__ Wfin,
    const float* __restrict__ bfin, f16* __restrict__ wsh,
    float* __restrict__ wsf)
{
  int tid = blockIdx.x * 256 + threadIdx.x;
  if (tid < 65536) {
    // Wa: col<128 -> context-folded W1 ; col>=128 -> Wf1[e][d][hh] at col 128+e*32+hh
    int j = tid & 7, l = (tid >> 3) & 63, kt = (tid >> 9) & 7, nt = tid >> 12;
    int k = kt * 32 + ((l >> 4) << 3) + j, n = nt * 16 + (l & 15);
    float v;
    if (n < 128) v = ctx[k] * W1[k * 128 + n];
    else { int c = n - 128; v = Wf1[((c >> 5) * 256 + k) * 32 + (c & 31)]; }
    wsh[tid] = (f16)v;
  } else if (tid < WB_OFF + 18432) {
    int o = tid - WB_OFF;
    int j = o & 7, l = (o >> 3) & 63, kt = (o >> 9) & 3, nt = o >> 11;
    int k = kt * 32 + ((l >> 4) << 3) + j, n = nt * 16 + (l & 15);
    float v = (n < 128) ? W2[k * 128 + n] : W12[k * 16 + (n - 128)];
    wsh[tid] = (f16)v;
  } else if (tid < WC_OFF + 2048) {
    int o = tid - WC_OFF;
    int j = o & 7, l = (o >> 3) & 63, kt = (o >> 9) & 3;
    int k = kt * 32 + ((l >> 4) << 3) + j, n = l & 15;
    float v = (n < 4) ? W22[k * 4 + n] : 0.f;
    wsh[tid] = (f16)v;
  } else if (tid < WF2_OFF + 4096) {
    int o = tid - WF2_OFF;
    int j = o & 7, l = (o >> 3) & 63, ent = o >> 9;
    int e = ent >> 1, nt = ent & 1;
    int k = ((l >> 4) << 3) + j, n = nt * 16 + (l & 15);
    wsh[tid] = (f16)Wf2[(e * 32 + k) * 32 + n];
  } else if (tid < 90112 + 565) {
    int o = tid - 90112;
    float v;
    if (o < 128) v = b1[o];
    else if (o < 256) v = bf1[o - 128];
    else if (o < 384) v = b2[o - 256];
    else if (o < 400) v = b12[o - 384];
    else if (o < 404) v = b22[o - 400];
    else if (o < 532) v = bf2[o - 404];
    else if (o < 564) v = Wfin[o - 532];
    else v = bfin[0];
    wsf[o] = v;
  }
}

#define MFMA16(A, Bv, C) __builtin_amdgcn_mfma_f32_16x16x32_f16(A, Bv, C, 0, 0, 0)

// LDS map (bytes):
// phase1: sX 0..32767 ([64][256] f16, swizzled)
// sH  32768..49151 ([64][128] f16)  : h, later reused for in2
// sO1 49152..65535 ([64][128] f16)  : o1
// overlay inside old sX after GEMM1:
//   sH2 0..16383 ([64][128] f16), sL1 16384 ([64][16] f32),
//   sL2 20480 ([64][4] f32), sC1 24576 ([64][16] f32),
//   sC2 28672 ([64][4] f32), sPart 29696 ([4][64] f32)
__global__ __launch_bounds__(256, 2) void fused_kernel(
    const float* __restrict__ x, const f16* __restrict__ wsh,
    const float* __restrict__ wsf, float* __restrict__ out)
{
  __shared__ __attribute__((aligned(16))) char lds[65536];
  const int t = threadIdx.x;
  const int lane = t & 63;
  const int w = t >> 6;
  const int l15 = lane & 15;
  const int l4 = lane >> 4;
  const size_t base = (size_t)blockIdx.x * BM;

  // ---- stage x tile -> sX (f16, swizzled) ----
#pragma unroll
  for (int it = 0; it < 8; ++it) {
    int c = it * 256 + t;
    int r = c >> 5;
    int k0 = (c & 31) << 3;
    const float4* xv = (const float4*)(x + (base + (size_t)r) * 256 + k0);
    float4 a = xv[0], b = xv[1];
    half8 hv;
    hv[0] = (f16)a.x; hv[1] = (f16)a.y; hv[2] = (f16)a.z; hv[3] = (f16)a.w;
    hv[4] = (f16)b.x; hv[5] = (f16)b.y; hv[6] = (f16)b.z; hv[7] = (f16)b.w;
    int addr = (r * 512 + k0 * 2) ^ ((r & 7) << 4);
    *(half8*)(lds + addr) = hv;
  }
  __syncthreads();

  // ---- GEMM1: G = relu(X @ Wa + ba); cols<128 -> sH (h), >=128 -> sO1 (o1) ----
  {
    floatx4 acc[4][4];
#pragma unroll
    for (int q = 0; q < 4; ++q)
#pragma unroll
      for (int mt = 0; mt < 4; ++mt) acc[q][mt] = (floatx4){0.f, 0.f, 0.f, 0.f};
    for (int kt = 0; kt < 8; ++kt) {
      half8 Af[4];
#pragma unroll
      for (int mt = 0; mt < 4; ++mt) {
        int r = mt * 16 + l15;
        int addr = (r * 512 + kt * 64 + (l4 << 4)) ^ ((r & 7) << 4);
        Af[mt] = *(const half8*)(lds + addr);
      }
#pragma unroll
      for (int q = 0; q < 4; ++q) {
        int nt = w * 4 + q;
        half8 Bf = *(const half8*)(wsh + WA_OFF + (size_t)((nt * 8 + kt) * 64 + lane) * 8);
#pragma unroll
        for (int mt = 0; mt < 4; ++mt) acc[q][mt] = MFMA16(Af[mt], Bf, acc[q][mt]);
      }
    }
#pragma unroll
    for (int q = 0; q < 4; ++q) {
      int col = (w * 4 + q) * 16 + l15;
      float bias = wsf[BA_OFF + col];
#pragma unroll
      for (int mt = 0; mt < 4; ++mt) {
#pragma unroll
        for (int i = 0; i < 4; ++i) {
          int r = mt * 16 + (l4 << 2) + i;
          float v = fmaxf(acc[q][mt][i] + bias, 0.f);
          int addr = (col < 128) ? (32768 + r * 256 + col * 2)
                                 : (49152 + r * 256 + (col - 128) * 2);
          *(f16*)(lds + (addr ^ ((r & 7) << 4))) = (f16)v;
        }
      }
    }
  }
  __syncthreads();

  // ---- GEMM2: h @ [W2 | W12] -> h2 (relu, sH2), L1 (sL1) ----
  {
    floatx4 acc2[2][4];
    floatx4 accL[4];
#pragma unroll
    for (int qi = 0; qi < 2; ++qi)
#pragma unroll
      for (int mt = 0; mt < 4; ++mt) acc2[qi][mt] = (floatx4){0.f, 0.f, 0.f, 0.f};
#pragma unroll
    for (int mt = 0; mt < 4; ++mt) accL[mt] = (floatx4){0.f, 0.f, 0.f, 0.f};

    for (int kt = 0; kt < 4; ++kt) {
      half8 Af[4];
#pragma unroll
      for (int mt = 0; mt < 4; ++mt) {
        int r = mt * 16 + l15;
        int addr = (32768 + r * 256 + kt * 64 + (l4 << 4)) ^ ((r & 7) << 4);
        Af[mt] = *(const half8*)(lds + addr);
      }
#pragma unroll
      for (int qi = 0; qi < 2; ++qi) {
        int nt = w + qi * 4;
        half8 Bf = *(const half8*)(wsh + WB_OFF + (size_t)((nt * 4 + kt) * 64 + lane) * 8);
#pragma unroll
        for (int mt = 0; mt < 4; ++mt) acc2[qi][mt] = MFMA16(Af[mt], Bf, acc2[qi][mt]);
      }
      if (w == 3) {
        half8 Bf = *(const half8*)(wsh + WB_OFF + (size_t)((32 + kt) * 64 + lane) * 8);
#pragma unroll
        for (int mt = 0; mt < 4; ++mt) accL[mt] = MFMA16(Af[mt], Bf, accL[mt]);
      }
    }
#pragma unroll
    for (int qi = 0; qi < 2; ++qi) {
      int col = (w + qi * 4) * 16 + l15;
      float bias = wsf[BB_OFF + col];
#pragma unroll
      for (int mt = 0; mt < 4; ++mt)
#pragma unroll
        for (int i = 0; i < 4; ++i) {
          int r = mt * 16 + (l4 << 2) + i;
          float v = fmaxf(acc2[qi][mt][i] + bias, 0.f);
          int addr = (r * 256 + col * 2) ^ ((r & 7) << 4);
          *(f16*)(lds + addr) = (f16)v;
        }
    }
    if (w == 3) {
      float bias = wsf[BB_OFF + 128 + l15];
#pragma unroll
      for (int mt = 0; mt < 4; ++mt)
#pragma unroll
        for (int i = 0; i < 4; ++i) {
          int r = mt * 16 + (l4 << 2) + i;
          *(float*)(lds + 16384 + r * 64 + l15 * 4) = accL[mt][i] + bias;
        }
    }
  }
  __syncthreads();

  // ---- GEMM3: h2 @ W22 -> L2 (wave w owns m-tile w) ----
  {
    floatx4 acc3 = (floatx4){0.f, 0.f, 0.f, 0.f};
#pragma unroll
    for (int kt = 0; kt < 4; ++kt) {
      int r = w * 16 + l15;
      int addr = (r * 256 + kt * 64 + (l4 << 4)) ^ ((r & 7) << 4);
      half8 Af = *(const half8*)(lds + addr);
      half8 Bf = *(const half8*)(wsh + WC_OFF + (size_t)(kt * 64 + lane) * 8);
      acc3 = MFMA16(Af, Bf, acc3);
    }
    if (l15 < 4) {
      float bias = wsf[BCC_OFF + l15];
#pragma unroll
      for (int i = 0; i < 4; ++i) {
        int r = w * 16 + (l4 << 2) + i;
        *(float*)(lds + 20480 + r * 16 + l15 * 4) = acc3[i] + bias;
      }
    }
  }
  __syncthreads();

  // ---- softmax: c1 (over experts, per f) and c2 ----
  {
    int row = t & 63, f = t >> 6;
    const float* L1 = (const float*)(lds + 16384);
    float a0 = L1[row * 16 + f],      a1 = L1[row * 16 + 4 + f];
    float a2 = L1[row * 16 + 8 + f],  a3 = L1[row * 16 + 12 + f];
    float m = fmaxf(fmaxf(a0, a1), fmaxf(a2, a3));
    float e0 = __expf(a0 - m), e1 = __expf(a1 - m), e2 = __expf(a2 - m), e3 = __expf(a3 - m);
    float inv = 1.f / (e0 + e1 + e2 + e3);
    float* C1 = (float*)(lds + 24576);
    C1[row * 16 + f] = e0 * inv;
    C1[row * 16 + 4 + f] = e1 * inv;
    C1[row * 16 + 8 + f] = e2 * inv;
    C1[row * 16 + 12 + f] = e3 * inv;
    if (f == 0) {
      const float* L2 = (const float*)(lds + 20480);
      float q0 = L2[row * 4 + 0], q1 = L2[row * 4 + 1];
      float q2 = L2[row * 4 + 2], q3 = L2[row * 4 + 3];
      float m2 = fmaxf(fmaxf(q0, q1), fmaxf(q2, q3));
      float f0 = __expf(q0 - m2), f1 = __expf(q1 - m2), f2 = __expf(q2 - m2), f3 = __expf(q3 - m2);
      float inv2 = 1.f / (f0 + f1 + f2 + f3);
      float* C2 = (float*)(lds + 28672);
      C2[row * 4 + 0] = f0 * inv2; C2[row * 4 + 1] = f1 * inv2;
      C2[row * 4 + 2] = f2 * inv2; C2[row * 4 + 3] = f3 * inv2;
    }
  }
  __syncthreads();

  // ---- in2[b][h][f] = sum_e o1[b][h][e] * c1[b][e][f]  -> sH[row][f*32+h] ----
  {
    int row = t & 63, f = t >> 6;
    const float* C1 = (const float*)(lds + 24576);
    float c0 = C1[row * 16 + f],     c1v = C1[row * 16 + 4 + f];
    float c2v = C1[row * 16 + 8 + f], c3v = C1[row * 16 + 12 + f];
    int sw = (row & 7) << 4;
#pragma unroll
    for (int h8 = 0; h8 < 4; ++h8) {
      half8 o0 = *(const half8*)(lds + ((49152 + row * 256 + 0   + h8 * 16) ^ sw));
      half8 o1v = *(const half8*)(lds + ((49152 + row * 256 + 64  + h8 * 16) ^ sw));
      half8 o2v = *(const half8*)(lds + ((49152 + row * 256 + 128 + h8 * 16) ^ sw));
      half8 o3v = *(const half8*)(lds + ((49152 + row * 256 + 192 + h8 * 16) ^ sw));
      half8 res;
#pragma unroll
      for (int j = 0; j < 8; ++j) {
        float v = c0 * (float)o0[j] + c1v * (float)o1v[j] + c2v * (float)o2v[j] + c3v * (float)o3v[j];
        res[j] = (f16)v;
      }
      *(half8*)(lds + ((32768 + row * 256 + f * 64 + h8 * 16) ^ sw)) = res;
    }
  }
  __syncthreads();

  // ---- GEMM4 (wave w = expert e): o2 = relu(in2_e @ Wf2_e + bf2_e); epilogue reduce ----
  {
    floatx4 acc4[2][4];
#pragma unroll
    for (int nt = 0; nt < 2; ++nt)
#pragma unroll
      for (int mt = 0; mt < 4; ++mt) acc4[nt][mt] = (floatx4){0.f, 0.f, 0.f, 0.f};
    half8 Af[4];
#pragma unroll
    for (int mt = 0; mt < 4; ++mt) {
      int r = mt * 16 + l15;
      int addr = (32768 + r * 256 + w * 64 + (l4 << 4)) ^ ((r & 7) << 4);
      Af[mt] = *(const half8*)(lds + addr);
    }
#pragma unroll
    for (int nt = 0; nt < 2; ++nt) {
      half8 Bf = *(const half8*)(wsh + WF2_OFF + (size_t)((w * 2 + nt) * 64 + lane) * 8);
#pragma unroll
      for (int mt = 0; mt < 4; ++mt) acc4[nt][mt] = MFMA16(Af[mt], Bf, acc4[nt][mt]);
    }
    float b0 = wsf[BF2_OFF + w * 32 + l15];
    float b1v = wsf[BF2_OFF + w * 32 + 16 + l15];
    float wf0 = wsf[WFIN_OFF + l15];
    float wf1 = wsf[WFIN_OFF + 16 + l15];
#pragma unroll
    for (int mt = 0; mt < 4; ++mt) {
      float v[4];
#pragma unroll
      for (int i = 0; i < 4; ++i) {
        int r = mt * 16 + (l4 << 2) + i;
        float c2e = *(const float*)(lds + 28672 + r * 16 + w * 4);
        float s = fmaxf(acc4[0][mt][i] + b0, 0.f) * wf0
                + fmaxf(acc4[1][mt][i] + b1v, 0.f) * wf1;
        v[i] = s * c2e;
      }
#pragma unroll
      for (int off = 1; off < 16; off <<= 1) {
#pragma unroll
        for (int i = 0; i < 4; ++i) v[i] += __shfl_xor(v[i], off);
      }
      if (l15 == 0) {
#pragma unroll
        for (int i = 0; i < 4; ++i) {
          int r = mt * 16 + (l4 << 2) + i;
          *(float*)(lds + 29696 + w * 256 + r * 4) = v[i];
        }
      }
    }
  }
  __syncthreads();

  if (t < 64) {
    float s = wsf[BFIN_OFF];
#pragma unroll
    for (int e = 0; e < 4; ++e) s += *(const float*)(lds + 29696 + e * 256 + t * 4);
    out[base + t] = s;
  }
}

extern "C" void kernel_launch(void* const* d_in, const int* in_sizes, int n_in,
                              void* d_out, int out_size, void* d_ws, size_t ws_size,
                              hipStream_t stream) {
  (void)in_sizes; (void)n_in; (void)ws_size;
  const float* x    = (const float*)d_in[0];
  const float* ctx  = (const float*)d_in[1];
  const float* W1   = (const float*)d_in[2];
  const float* b1   = (const float*)d_in[3];
  const float* W2   = (const float*)d_in[4];
  const float* b2   = (const float*)d_in[5];
  const float* W12  = (const float*)d_in[6];
  const float* b12  = (const float*)d_in[7];
  const float* W22  = (const float*)d_in[8];
  const float* b22  = (const float*)d_in[9];
  const float* Wf1  = (const float*)d_in[10];
  const float* bf1  = (const float*)d_in[11];
  const float* Wf2  = (const float*)d_in[12];
  const float* bf2  = (const float*)d_in[13];
  const float* Wfin = (const float*)d_in[14];
  const float* bfin = (const float*)d_in[15];

  f16* wsh = (f16*)d_ws;
  float* wsf = (float*)((char*)d_ws + WSF_BYTE_OFF);

  prep_kernel<<<355, 256, 0, stream>>>(ctx, W1, b1, W2, b2, W12, b12, W22, b22,
                                       Wf1, bf1, Wf2, bf2, Wfin, bfin, wsh, wsf);

  int nblocks = 262144 / BM;  // 4096
  fused_kernel<<<nblocks, 256, 0, stream>>>(x, wsh, wsf, (float*)d_out);
}

// Round 2
// 102.419 us; speedup vs baseline: 1.4549x; 1.4549x over previous
//
#include <hip/hip_runtime.h>
#include <hip/hip_bf16.h>

typedef _Float16 f16;
typedef _Float16 half8 __attribute__((ext_vector_type(8)));
typedef _Float16 half4 __attribute__((ext_vector_type(4)));
typedef float floatx4 __attribute__((ext_vector_type(4)));

#define BM 64

// ---- ws layout (f16 element offsets) ----
#define WA_OFF 0         // 65536 f16 : WaT frag order (CT=16,KT=8) — A-operand of swapped GEMM1
#define WB_OFF 65536     // 18432 f16 : WbT (CT=9, KT=4)  ct: 0-7=W2, 8=W12
#define WC_OFF 83968     // 2048 f16  : WcT (CT=1, KT=4)  rows 0-3 = W22 cols
#define WF2_OFF 86016    // 4096 f16  : Wf2T [4][CT=2,KT=1]
#define WSF_BYTE_OFF 180224
// wsf (float offsets)
#define BA_OFF 0      // 256: b1 | bf1
#define BB_OFF 256    // 144: b2 | b12
#define BCC_OFF 400   // 4  : b22
#define BF2_OFF 404   // 128: bf2
#define WFIN_OFF 532  // 32
#define BFIN_OFF 564  // 1

__global__ __launch_bounds__(256) void prep_kernel(
    const float* __restrict__ ctx, const float* __restrict__ W1,
    const float* __restrict__ b1, const float* __restrict__ W2,
    const float* __restrict__ b2, const float* __restrict__ W12,
    const float* __restrict__ b12, const float* __restrict__ W22,
    const float* __restrict__ b22, const float* __restrict__ Wf1,
    const float* __restrict__ bf1, const float* __restrict__ Wf2,
    const float* __restrict__ bf2, const float* __restrict__ Wfin,
    const float* __restrict__ bfin, f16* __restrict__ wsh,
    float* __restrict__ wsf)
{
  int tid = blockIdx.x * 256 + threadIdx.x;
  if (tid < 65536) {
    int j = tid & 7, l = (tid >> 3) & 63, kt = (tid >> 9) & 7, nt = tid >> 12;
    int k = kt * 32 + ((l >> 4) << 3) + j, n = nt * 16 + (l & 15);
    float v;
    if (n < 128) v = ctx[k] * W1[k * 128 + n];
    else { int c = n - 128; v = Wf1[((c >> 5) * 256 + k) * 32 + (c & 31)]; }
    wsh[tid] = (f16)v;
  } else if (tid < WB_OFF + 18432) {
    int o = tid - WB_OFF;
    int j = o & 7, l = (o >> 3) & 63, kt = (o >> 9) & 3, nt = o >> 11;
    int k = kt * 32 + ((l >> 4) << 3) + j, n = nt * 16 + (l & 15);
    float v = (n < 128) ? W2[k * 128 + n] : W12[k * 16 + (n - 128)];
    wsh[tid] = (f16)v;
  } else if (tid < WC_OFF + 2048) {
    int o = tid - WC_OFF;
    int j = o & 7, l = (o >> 3) & 63, kt = (o >> 9) & 3;
    int k = kt * 32 + ((l >> 4) << 3) + j, n = l & 15;
    float v = (n < 4) ? W22[k * 4 + n] : 0.f;
    wsh[tid] = (f16)v;
  } else if (tid < WF2_OFF + 4096) {
    int o = tid - WF2_OFF;
    int j = o & 7, l = (o >> 3) & 63, ent = o >> 9;
    int e = ent >> 1, nt = ent & 1;
    int k = ((l >> 4) << 3) + j, n = nt * 16 + (l & 15);
    wsh[tid] = (f16)Wf2[(e * 32 + k) * 32 + n];
  } else if (tid < 90112 + 565) {
    int o = tid - 90112;
    float v;
    if (o < 128) v = b1[o];
    else if (o < 256) v = bf1[o - 128];
    else if (o < 384) v = b2[o - 256];
    else if (o < 400) v = b12[o - 384];
    else if (o < 404) v = b22[o - 400];
    else if (o < 532) v = bf2[o - 404];
    else if (o < 564) v = Wfin[o - 532];
    else v = bfin[0];
    wsf[o] = v;
  }
}

#define MFMA16(A, Bv, C) __builtin_amdgcn_mfma_f32_16x16x32_f16(A, Bv, C, 0, 0, 0)

// LDS map (bytes), 52 KB total -> 3 blocks/CU:
//  G    0..32767   [64][256] f16 swz : x-tile, then h (c<128) | o1 (c>=128)
//  H2   32768..49151 [64][128] f16 swz : h2, then in2 [64][4e][32h]
//  L1   49152..51199 [64][16] f16 : logits1 ; overlaid by part [4][64] f32 in G4
//  L2   51200..52223 [64][4] f32
//  C2   52224..53247 [64][4] f32
#define G_OFF 0
#define H2_OFF 32768
#define L1_OFF 49152
#define PART_OFF 49152
#define L2_OFF 51200
#define C2_OFF 52224

__global__ __launch_bounds__(256, 3) void fused_kernel(
    const float* __restrict__ x, const f16* __restrict__ wsh,
    const float* __restrict__ wsf, float* __restrict__ out)
{
  __shared__ __attribute__((aligned(16))) char lds[53248];
  const int t = threadIdx.x;
  const int lane = t & 63;
  const int w = t >> 6;
  const int l15 = lane & 15;
  const int l4 = lane >> 4;
  const size_t base = (size_t)blockIdx.x * BM;

  // ---- stage x tile -> G (f16, swizzled) ----
#pragma unroll
  for (int it = 0; it < 8; ++it) {
    int c = it * 256 + t;
    int r = c >> 5;
    int k0 = (c & 31) << 3;
    const float4* xv = (const float4*)(x + (base + (size_t)r) * 256 + k0);
    float4 a = xv[0], b = xv[1];
    half8 hv;
    hv[0] = (f16)a.x; hv[1] = (f16)a.y; hv[2] = (f16)a.z; hv[3] = (f16)a.w;
    hv[4] = (f16)b.x; hv[5] = (f16)b.y; hv[6] = (f16)b.z; hv[7] = (f16)b.w;
    int addr = (r * 512 + k0 * 2) ^ ((r & 7) << 4);
    *(half8*)(lds + addr) = hv;
  }
  __syncthreads();  // b0

  // ---- GEMM1 (swapped: A=WaT, B=x): G-out = relu(...) ----
  floatx4 acc[4][4];
#pragma unroll
  for (int q = 0; q < 4; ++q)
#pragma unroll
    for (int mt = 0; mt < 4; ++mt) acc[q][mt] = (floatx4){0.f, 0.f, 0.f, 0.f};
  for (int kt = 0; kt < 8; ++kt) {
    half8 Bx[4];
#pragma unroll
    for (int mt = 0; mt < 4; ++mt) {
      int r = mt * 16 + l15;
      int addr = (r * 512 + kt * 64 + (l4 << 4)) ^ ((r & 7) << 4);
      Bx[mt] = *(const half8*)(lds + addr);
    }
#pragma unroll
    for (int q = 0; q < 4; ++q) {
      half8 Wf = *(const half8*)(wsh + WA_OFF + (size_t)(((w * 4 + q) * 8 + kt) * 64 + lane) * 8);
#pragma unroll
      for (int mt = 0; mt < 4; ++mt) acc[q][mt] = MFMA16(Wf, Bx[mt], acc[q][mt]);
    }
  }
  __syncthreads();  // b1: all x reads done before overlay writes
#pragma unroll
  for (int q = 0; q < 4; ++q) {
    int c0 = (w * 4 + q) * 16 + l4 * 4;
    float4 bias = *(const float4*)(wsf + BA_OFF + c0);
#pragma unroll
    for (int mt = 0; mt < 4; ++mt) {
      int r = mt * 16 + l15;
      half4 hv;
#pragma unroll
      for (int i = 0; i < 4; ++i) hv[i] = (f16)fmaxf(acc[q][mt][i] + ((const float*)&bias)[i], 0.f);
      int addr = (r * 512 + c0 * 2) ^ ((r & 7) << 4);
      *(half4*)(lds + addr) = hv;
    }
  }
  __syncthreads();  // b2

  // ---- GEMM2: h2 = relu(h @ W2), L1 = h @ W12 ----
  {
    floatx4 acc2[2][4];
    floatx4 accL[4];
#pragma unroll
    for (int qi = 0; qi < 2; ++qi)
#pragma unroll
      for (int mt = 0; mt < 4; ++mt) acc2[qi][mt] = (floatx4){0.f, 0.f, 0.f, 0.f};
#pragma unroll
    for (int mt = 0; mt < 4; ++mt) accL[mt] = (floatx4){0.f, 0.f, 0.f, 0.f};

    for (int kt = 0; kt < 4; ++kt) {
      half8 Bh[4];
#pragma unroll
      for (int mt = 0; mt < 4; ++mt) {
        int r = mt * 16 + l15;
        int addr = (r * 512 + kt * 64 + (l4 << 4)) ^ ((r & 7) << 4);
        Bh[mt] = *(const half8*)(lds + addr);
      }
#pragma unroll
      for (int qi = 0; qi < 2; ++qi) {
        half8 Wf = *(const half8*)(wsh + WB_OFF + (size_t)(((w + qi * 4) * 4 + kt) * 64 + lane) * 8);
#pragma unroll
        for (int mt = 0; mt < 4; ++mt) acc2[qi][mt] = MFMA16(Wf, Bh[mt], acc2[qi][mt]);
      }
      if (w == 3) {
        half8 Wf = *(const half8*)(wsh + WB_OFF + (size_t)((32 + kt) * 64 + lane) * 8);
#pragma unroll
        for (int mt = 0; mt < 4; ++mt) accL[mt] = MFMA16(Wf, Bh[mt], accL[mt]);
      }
    }
    // epilogue: writes H2/L1 (disjoint from G reads) — no barrier needed first
#pragma unroll
    for (int qi = 0; qi < 2; ++qi) {
      int c0 = (w + qi * 4) * 16 + l4 * 4;
      float4 bias = *(const float4*)(wsf + BB_OFF + c0);
#pragma unroll
      for (int mt = 0; mt < 4; ++mt) {
        int r = mt * 16 + l15;
        half4 hv;
#pragma unroll
        for (int i = 0; i < 4; ++i) hv[i] = (f16)fmaxf(acc2[qi][mt][i] + ((const float*)&bias)[i], 0.f);
        int addr = H2_OFF + ((r * 256 + c0 * 2) ^ ((r & 7) << 4));
        *(half4*)(lds + addr) = hv;
      }
    }
    if (w == 3) {
      int c0 = l4 * 4;
      float4 bias = *(const float4*)(wsf + BB_OFF + 128 + c0);
#pragma unroll
      for (int mt = 0; mt < 4; ++mt) {
        int r = mt * 16 + l15;
        half4 hv;
#pragma unroll
        for (int i = 0; i < 4; ++i) hv[i] = (f16)(accL[mt][i] + ((const float*)&bias)[i]);
        *(half4*)(lds + L1_OFF + r * 32 + c0 * 2) = hv;
      }
    }
  }
  __syncthreads();  // b3

  // ---- GEMM3: L2 = h2 @ W22 (wave w owns rows w*16..w*16+15) ----
  {
    floatx4 acc3 = (floatx4){0.f, 0.f, 0.f, 0.f};
    int r = w * 16 + l15;
#pragma unroll
    for (int kt = 0; kt < 4; ++kt) {
      int addr = H2_OFF + ((r * 256 + kt * 64 + (l4 << 4)) ^ ((r & 7) << 4));
      half8 Bh2 = *(const half8*)(lds + addr);
      half8 Wf = *(const half8*)(wsh + WC_OFF + (size_t)(kt * 64 + lane) * 8);
      acc3 = MFMA16(Wf, Bh2, acc3);
    }
    if (lane < 16) {
      float4 bias = *(const float4*)(wsf + BCC_OFF);
      float4 v;
      v.x = acc3[0] + bias.x; v.y = acc3[1] + bias.y;
      v.z = acc3[2] + bias.z; v.w = acc3[3] + bias.w;
      *(float4*)(lds + L2_OFF + (w * 16 + lane) * 16) = v;
    }
  }
  __syncthreads();  // b4

  // ---- c1 softmax + in2 mix (+ c2 softmax); in2 overlays h2 ----
  {
    int r = t >> 2, f = t & 3;
    const f16* L1p = (const f16*)(lds + L1_OFF) + r * 16 + f;
    float a0 = (float)L1p[0], a1 = (float)L1p[4], a2 = (float)L1p[8], a3 = (float)L1p[12];
    float m = fmaxf(fmaxf(a0, a1), fmaxf(a2, a3));
    float e0 = __expf(a0 - m), e1 = __expf(a1 - m), e2 = __expf(a2 - m), e3 = __expf(a3 - m);
    float inv = 1.f / (e0 + e1 + e2 + e3);
    float c0v = e0 * inv, c1v = e1 * inv, c2v = e2 * inv, c3v = e3 * inv;
    int sw = (r & 7) << 4;
#pragma unroll
    for (int h8 = 0; h8 < 4; ++h8) {
      half8 o0 = *(const half8*)(lds + ((r * 512 + 256 + 0   + h8 * 16) ^ sw));
      half8 o1v = *(const half8*)(lds + ((r * 512 + 256 + 64  + h8 * 16) ^ sw));
      half8 o2v = *(const half8*)(lds + ((r * 512 + 256 + 128 + h8 * 16) ^ sw));
      half8 o3v = *(const half8*)(lds + ((r * 512 + 256 + 192 + h8 * 16) ^ sw));
      half8 res;
#pragma unroll
      for (int j = 0; j < 8; ++j) {
        float v = c0v * (float)o0[j] + c1v * (float)o1v[j] + c2v * (float)o2v[j] + c3v * (float)o3v[j];
        res[j] = (f16)v;
      }
      *(half8*)(lds + H2_OFF + ((r * 256 + f * 64 + h8 * 16) ^ sw)) = res;
    }
    if (f == 0) {
      float4 q = *(const float4*)(lds + L2_OFF + r * 16);
      float m2 = fmaxf(fmaxf(q.x, q.y), fmaxf(q.z, q.w));
      float f0 = __expf(q.x - m2), f1 = __expf(q.y - m2), f2 = __expf(q.z - m2), f3 = __expf(q.w - m2);
      float inv2 = 1.f / (f0 + f1 + f2 + f3);
      float4 c2o; c2o.x = f0 * inv2; c2o.y = f1 * inv2; c2o.z = f2 * inv2; c2o.w = f3 * inv2;
      *(float4*)(lds + C2_OFF + r * 16) = c2o;
    }
  }
  __syncthreads();  // b5

  // ---- GEMM4 (wave w = expert e) + fused Wfin reduce ----
  {
    floatx4 acc4[2][4];
#pragma unroll
    for (int ct = 0; ct < 2; ++ct)
#pragma unroll
      for (int mt = 0; mt < 4; ++mt) acc4[ct][mt] = (floatx4){0.f, 0.f, 0.f, 0.f};
    half8 Bi[4];
#pragma unroll
    for (int mt = 0; mt < 4; ++mt) {
      int r = mt * 16 + l15;
      int addr = H2_OFF + ((r * 256 + w * 64 + (l4 << 4)) ^ ((r & 7) << 4));
      Bi[mt] = *(const half8*)(lds + addr);
    }
#pragma unroll
    for (int ct = 0; ct < 2; ++ct) {
      half8 Wf = *(const half8*)(wsh + WF2_OFF + (size_t)((w * 2 + ct) * 64 + lane) * 8);
#pragma unroll
      for (int mt = 0; mt < 4; ++mt) acc4[ct][mt] = MFMA16(Wf, Bi[mt], acc4[ct][mt]);
    }
    float4 bias0 = *(const float4*)(wsf + BF2_OFF + w * 32 + l4 * 4);
    float4 bias1 = *(const float4*)(wsf + BF2_OFF + w * 32 + 16 + l4 * 4);
    float4 wf0 = *(const float4*)(wsf + WFIN_OFF + l4 * 4);
    float4 wf1 = *(const float4*)(wsf + WFIN_OFF + 16 + l4 * 4);
#pragma unroll
    for (int mt = 0; mt < 4; ++mt) {
      int r = mt * 16 + l15;
      float s = 0.f;
#pragma unroll
      for (int i = 0; i < 4; ++i) {
        s += fmaxf(acc4[0][mt][i] + ((const float*)&bias0)[i], 0.f) * ((const float*)&wf0)[i];
        s += fmaxf(acc4[1][mt][i] + ((const float*)&bias1)[i], 0.f) * ((const float*)&wf1)[i];
      }
      s += __shfl_xor(s, 16);
      s += __shfl_xor(s, 32);
      if (l4 == 0) {
        float c2e = *(const float*)(lds + C2_OFF + r * 16 + w * 4);
        *(float*)(lds + PART_OFF + (w * 64 + r) * 4) = s * c2e;
      }
    }
  }
  __syncthreads();  // b6

  if (t < 64) {
    float s = wsf[BFIN_OFF];
#pragma unroll
    for (int e = 0; e < 4; ++e) s += *(const float*)(lds + PART_OFF + e * 256 + t * 4);
    out[base + t] = s;
  }
}

extern "C" void kernel_launch(void* const* d_in, const int* in_sizes, int n_in,
                              void* d_out, int out_size, void* d_ws, size_t ws_size,
                              hipStream_t stream) {
  (void)in_sizes; (void)n_in; (void)ws_size;
  const float* x    = (const float*)d_in[0];
  const float* ctx  = (const float*)d_in[1];
  const float* W1   = (const float*)d_in[2];
  const float* b1   = (const float*)d_in[3];
  const float* W2   = (const float*)d_in[4];
  const float* b2   = (const float*)d_in[5];
  const float* W12  = (const float*)d_in[6];
  const float* b12  = (const float*)d_in[7];
  const float* W22  = (const float*)d_in[8];
  const float* b22  = (const float*)d_in[9];
  const float* Wf1  = (const float*)d_in[10];
  const float* bf1  = (const float*)d_in[11];
  const float* Wf2  = (const float*)d_in[12];
  const float* bf2  = (const float*)d_in[13];
  const float* Wfin = (const float*)d_in[14];
  const float* bfin = (const float*)d_in[15];

  f16* wsh = (f16*)d_ws;
  float* wsf = (float*)((char*)d_ws + WSF_BYTE_OFF);

  prep_kernel<<<355, 256, 0, stream>>>(ctx, W1, b1, W2, b2, W12, b12, W22, b22,
                                       Wf1, bf1, Wf2, bf2, Wfin, bfin, wsh, wsf);

  int nblocks = 262144 / BM;  // 4096
  fused_kernel<<<nblocks, 256, 0, stream>>>(x, wsh, wsf, (float*)d_out);
}